// Round 7
// baseline (304.567 us; speedup 1.0000x reference)
//
#include <hip/hip_runtime.h>

// GNN: 2x SAGEConv(sum) + global_add_pool + Linear head.
// N=50000 nodes, E=1e6 edges, D=H=64, G=512 graphs, O=16.
//
// R1: CSR gather replaced scatter atomics (2111 -> 606 us).
// R2: sorted-segment pooling replaced atomic pooling (606 -> 395 us).
// R3: binned counting sort for CSR build (395 -> 367 us).
// R4: bf16 feature storage end-to-end, fp32 accumulate (367 -> 325 us).
// R5: bucket-local degree counting replaced global hist (325 -> 302 us).
// R6: scan-free CSR via fixed per-bucket capacity slots (16000 >> max
// bucket ~10.5K): single-pass bucket scatter + one merged bucket_sort
// kernel (LDS hist+scan+place; 1M global cursor atomics -> LDS). col as
// ushort, (beg<<11|deg) packed meta, grid-stride GEMM (weights staged
// 256x not 782x). 10 launches (was 14).

namespace {
constexpr int NN = 50000;
constexpr int NE = 1000000;
constexpr int NG = 512;
constexpr int NO = 16;
constexpr int KB = 98;                      // buckets: dst>>9 (512 nodes)
constexpr int BCAP = 16000;                 // slot capacity per bucket
constexpr int EPT = 8;                      // edges per thread (scatter)
constexpr int EPB = 256 * EPT;              // 2048 edges per block
constexpr int SBLK = (NE + EPB - 1) / EPB;  // 489 blocks
constexpr int SEDGE = 12288;                // staged edges in bucket_sort
}

__device__ __forceinline__ unsigned short f2bf(float f) {
  unsigned u = __float_as_uint(f);
  u += 0x7FFFu + ((u >> 16) & 1u);  // round-to-nearest-even
  return (unsigned short)(u >> 16);
}
__device__ __forceinline__ float bf2f(unsigned short s) {
  return __uint_as_float(((unsigned)s) << 16);
}

// ---------------- CSR build (scan-free bucketed counting sort) -------------

// Single pass: LDS-binned scatter of packed edges into fixed-capacity
// bucket slots of ebuf. bcount[b] accumulates bucket sizes (48K atomics).
__global__ __launch_bounds__(256) void bucket_scatter(
    const int* __restrict__ ei, int* __restrict__ bcount,
    unsigned int* __restrict__ ebuf) {
  __shared__ int cnt[KB];
  __shared__ int base[KB];
  int t = threadIdx.x;
  if (t < KB) cnt[t] = 0;
  __syncthreads();
  int e0 = blockIdx.x * EPB;
  unsigned int pk[EPT];
#pragma unroll
  for (int i = 0; i < EPT; ++i) {
    int e = e0 + i * 256 + t;
    if (e < NE) {
      unsigned int src = (unsigned int)ei[e];
      unsigned int dst = (unsigned int)ei[NE + e];
      pk[i] = (dst << 16) | src;
      atomicAdd(&cnt[dst >> 9], 1);
    } else {
      pk[i] = 0xFFFFFFFFu;
    }
  }
  __syncthreads();
  if (t < KB) {
    base[t] = t * BCAP + atomicAdd(&bcount[t], cnt[t]);
    cnt[t] = 0;
  }
  __syncthreads();
#pragma unroll
  for (int i = 0; i < EPT; ++i) {
    if (pk[i] != 0xFFFFFFFFu) {
      int b = pk[i] >> 25;  // dst >> 9
      int r = atomicAdd(&cnt[b], 1);
      ebuf[base[b] + r] = pk[i];
    }
  }
}

// One 512-thread block per bucket: stage edges in LDS, LDS degree
// histogram, LDS scan, LDS-cursor placement into col (ushort, bucket
// window), emit meta[node] = (col_beg << 11) | deg.
__global__ __launch_bounds__(512) void bucket_sort(
    const unsigned int* __restrict__ ebuf, const int* __restrict__ bcount,
    unsigned int* __restrict__ meta, unsigned short* __restrict__ col) {
  __shared__ unsigned int se[SEDGE];  // 48 KB edge stage
  __shared__ int cnt[512];
  __shared__ int cur[512];
  int b = blockIdx.x;
  int t = threadIdx.x;
  int n = bcount[b];
  const unsigned int* eb = ebuf + (size_t)b * BCAP;
  cnt[t] = 0;
  __syncthreads();
  for (int j = t; j < n; j += 512) {
    unsigned int p = eb[j];
    if (j < SEDGE) se[j] = p;
    atomicAdd(&cnt[(p >> 16) & 511], 1);
  }
  __syncthreads();
  int deg = cnt[t];
  // Hillis-Steele inclusive scan over 512 (read-all / sync / write / sync)
  for (int off = 1; off < 512; off <<= 1) {
    int u = (t >= off) ? cnt[t - off] : 0;
    __syncthreads();
    cnt[t] += u;
    __syncthreads();
  }
  int excl = cnt[t] - deg;
  cur[t] = excl;
  int node = (b << 9) + t;
  if (node < NN) {
    meta[node] = ((unsigned)(b * BCAP + excl) << 11) | (unsigned)deg;
  }
  __syncthreads();
  unsigned short* cb = col + (size_t)b * BCAP;
  for (int j = t; j < n; j += 512) {
    unsigned int p = (j < SEDGE) ? se[j] : eb[j];
    int d = (p >> 16) & 511;
    int pos = atomicAdd(&cur[d], 1);
    cb[pos] = (unsigned short)(p & 0xFFFFu);
  }
}

// ---------------- bf16 conversion ----------------
__global__ __launch_bounds__(256) void cvt_f32_bf16(
    const float* __restrict__ in, unsigned short* __restrict__ out, int n8) {
  int i = blockIdx.x * 256 + threadIdx.x;
  if (i >= n8) return;
  const float4* p = reinterpret_cast<const float4*>(in + (size_t)i * 8);
  float4 a = p[0], b = p[1];
  uint4 u;
  u.x = (unsigned)f2bf(a.x) | ((unsigned)f2bf(a.y) << 16);
  u.y = (unsigned)f2bf(a.z) | ((unsigned)f2bf(a.w) << 16);
  u.z = (unsigned)f2bf(b.x) | ((unsigned)f2bf(b.y) << 16);
  u.w = (unsigned)f2bf(b.z) | ((unsigned)f2bf(b.w) << 16);
  reinterpret_cast<uint4*>(out)[i] = u;
}

// ---------------- aggregation (gather, bf16, no atomics) ----------------
// 8 threads per node, one 16B uint4 (8 bf16) per thread per neighbor:
// each edge touches exactly one 128B line. fp32 accumulate, bf16 store.
__global__ __launch_bounds__(256) void gather_csr_bf(
    const unsigned short* __restrict__ feat, const unsigned int* __restrict__ meta,
    const unsigned short* __restrict__ col, unsigned short* __restrict__ agg) {
  int gid = blockIdx.x * 256 + threadIdx.x;
  int v = gid >> 3;
  int q = gid & 7;
  if (v >= NN) return;
  unsigned int m = meta[v];
  int beg = (int)(m >> 11);
  int end = beg + (int)(m & 2047u);
  float acc[8] = {0.f, 0.f, 0.f, 0.f, 0.f, 0.f, 0.f, 0.f};
  const uint4* fb = reinterpret_cast<const uint4*>(feat);
  for (int j = beg; j < end; ++j) {
    int s = col[j];
    uint4 u = fb[(size_t)s * 8 + q];
    acc[0] += __uint_as_float(u.x << 16);
    acc[1] += __uint_as_float(u.x & 0xFFFF0000u);
    acc[2] += __uint_as_float(u.y << 16);
    acc[3] += __uint_as_float(u.y & 0xFFFF0000u);
    acc[4] += __uint_as_float(u.z << 16);
    acc[5] += __uint_as_float(u.z & 0xFFFF0000u);
    acc[6] += __uint_as_float(u.w << 16);
    acc[7] += __uint_as_float(u.w & 0xFFFF0000u);
  }
  uint4 o;
  o.x = (unsigned)f2bf(acc[0]) | ((unsigned)f2bf(acc[1]) << 16);
  o.y = (unsigned)f2bf(acc[2]) | ((unsigned)f2bf(acc[3]) << 16);
  o.z = (unsigned)f2bf(acc[4]) | ((unsigned)f2bf(acc[5]) << 16);
  o.w = (unsigned)f2bf(acc[6]) | ((unsigned)f2bf(acc[7]) << 16);
  reinterpret_cast<uint4*>(agg)[(size_t)v * 8 + q] = o;
}

// ---------------- fused GEMM (bf16 in/out, fp32 math) ----------------
// out[row,:] = relu(A[row,:] @ Wl + Hr[row,:] @ Wr + b)
// 256 grid-stride blocks (weights staged once per block, not per 64 rows).
// Block = 256 threads = 64 rows x 4 col-chunks of 16. Weights fp32 in LDS.
// Called with out==A for layer 2 (in-place): each row is read/written only
// by its own 4 same-wave threads; loads precede stores in program order.
// A/out deliberately NOT __restrict__.
__global__ __launch_bounds__(256) void sage_lin_relu_bf(
    const unsigned short* A, const unsigned short* Hr,
    const float* __restrict__ Wl, const float* __restrict__ Wr,
    const float* __restrict__ bias, unsigned short* out) {
  __shared__ float sWl[64 * 64];
  __shared__ float sWr[64 * 64];
  int tid = threadIdx.x;
#pragma unroll
  for (int i = 0; i < 4; ++i) {
    int idx = i * 1024 + tid * 4;
    *reinterpret_cast<float4*>(sWl + idx) =
        *reinterpret_cast<const float4*>(Wl + idx);
    *reinterpret_cast<float4*>(sWr + idx) =
        *reinterpret_cast<const float4*>(Wr + idx);
  }
  __syncthreads();
  int r = tid >> 2, c = tid & 3;
  float bias_c[16];
#pragma unroll
  for (int j = 0; j < 16; ++j) bias_c[j] = bias[c * 16 + j];

  for (int rowb = blockIdx.x * 64; rowb < NN; rowb += 256 * 64) {
    int row = rowb + r;
    if (row >= NN) continue;  // no syncs below; divergence OK
    const uint4* A4 = reinterpret_cast<const uint4*>(A + (size_t)row * 64);
    const uint4* H4 = reinterpret_cast<const uint4*>(Hr + (size_t)row * 64);
    float acc[16];
#pragma unroll
    for (int j = 0; j < 16; ++j) acc[j] = bias_c[j];
#pragma unroll
    for (int k8 = 0; k8 < 8; ++k8) {
      uint4 ua = A4[k8];
      uint4 uh = H4[k8];
      float av[8], hv[8];
      av[0] = __uint_as_float(ua.x << 16);
      av[1] = __uint_as_float(ua.x & 0xFFFF0000u);
      av[2] = __uint_as_float(ua.y << 16);
      av[3] = __uint_as_float(ua.y & 0xFFFF0000u);
      av[4] = __uint_as_float(ua.z << 16);
      av[5] = __uint_as_float(ua.z & 0xFFFF0000u);
      av[6] = __uint_as_float(ua.w << 16);
      av[7] = __uint_as_float(ua.w & 0xFFFF0000u);
      hv[0] = __uint_as_float(uh.x << 16);
      hv[1] = __uint_as_float(uh.x & 0xFFFF0000u);
      hv[2] = __uint_as_float(uh.y << 16);
      hv[3] = __uint_as_float(uh.y & 0xFFFF0000u);
      hv[4] = __uint_as_float(uh.z << 16);
      hv[5] = __uint_as_float(uh.z & 0xFFFF0000u);
      hv[6] = __uint_as_float(uh.w << 16);
      hv[7] = __uint_as_float(uh.w & 0xFFFF0000u);
      const float* wl = sWl + k8 * 8 * 64 + c * 16;
      const float* wr = sWr + k8 * 8 * 64 + c * 16;
#pragma unroll
      for (int kk = 0; kk < 8; ++kk) {
#pragma unroll
        for (int j = 0; j < 16; ++j) {
          acc[j] += av[kk] * wl[kk * 64 + j] + hv[kk] * wr[kk * 64 + j];
        }
      }
    }
    uint4 o0, o1;
    float r0 = fmaxf(acc[0], 0.f), r1 = fmaxf(acc[1], 0.f);
    float r2 = fmaxf(acc[2], 0.f), r3 = fmaxf(acc[3], 0.f);
    float r4 = fmaxf(acc[4], 0.f), r5 = fmaxf(acc[5], 0.f);
    float r6 = fmaxf(acc[6], 0.f), r7 = fmaxf(acc[7], 0.f);
    o0.x = (unsigned)f2bf(r0) | ((unsigned)f2bf(r1) << 16);
    o0.y = (unsigned)f2bf(r2) | ((unsigned)f2bf(r3) << 16);
    o0.z = (unsigned)f2bf(r4) | ((unsigned)f2bf(r5) << 16);
    o0.w = (unsigned)f2bf(r6) | ((unsigned)f2bf(r7) << 16);
    float s0 = fmaxf(acc[8], 0.f), s1 = fmaxf(acc[9], 0.f);
    float s2 = fmaxf(acc[10], 0.f), s3 = fmaxf(acc[11], 0.f);
    float s4 = fmaxf(acc[12], 0.f), s5 = fmaxf(acc[13], 0.f);
    float s6 = fmaxf(acc[14], 0.f), s7 = fmaxf(acc[15], 0.f);
    o1.x = (unsigned)f2bf(s0) | ((unsigned)f2bf(s1) << 16);
    o1.y = (unsigned)f2bf(s2) | ((unsigned)f2bf(s3) << 16);
    o1.z = (unsigned)f2bf(s4) | ((unsigned)f2bf(s5) << 16);
    o1.w = (unsigned)f2bf(s6) | ((unsigned)f2bf(s7) << 16);
    uint4* op = reinterpret_cast<uint4*>(out + (size_t)row * 64 + c * 16);
    op[0] = o0;
    op[1] = o1;
  }
}

// ---------------- pooling (sorted-segment reduction) + head ----------------

__global__ __launch_bounds__(64) void graph_start_kernel(
    const int* __restrict__ batch, int* __restrict__ gstart) {
  int g = blockIdx.x * 64 + threadIdx.x;
  if (g > NG) return;
  int lo = 0, hi = NN;
  while (lo < hi) {
    int mid = (lo + hi) >> 1;
    if (batch[mid] < g)
      lo = mid + 1;
    else
      hi = mid;
  }
  gstart[g] = lo;
}

__global__ __launch_bounds__(64) void pool_head_kernel(
    const unsigned short* __restrict__ h2, const int* __restrict__ gstart,
    const float* __restrict__ Wo, const float* __restrict__ bo,
    float* __restrict__ out) {
  __shared__ float sm[64];
  int g = blockIdx.x;
  int c = threadIdx.x;
  int beg = gstart[g], end = gstart[g + 1];
  float acc = 0.f;
  for (int i = beg; i < end; ++i) acc += bf2f(h2[(size_t)i * 64 + c]);
  sm[c] = acc;
  __syncthreads();
  if (c < NO) {
    float o = bo[c];
#pragma unroll
    for (int k = 0; k < 64; ++k) o += sm[k] * Wo[k * 16 + c];
    out[g * 16 + c] = o;
  }
}

extern "C" void kernel_launch(void* const* d_in, const int* in_sizes, int n_in,
                              void* d_out, int out_size, void* d_ws,
                              size_t ws_size, hipStream_t stream) {
  const float* x = (const float*)d_in[0];
  const int* ei = (const int*)d_in[1];
  const int* batch = (const int*)d_in[2];
  const float* Wl1 = (const float*)d_in[3];
  const float* Wr1 = (const float*)d_in[4];
  const float* b1 = (const float*)d_in[5];
  const float* Wl2 = (const float*)d_in[6];
  const float* Wr2 = (const float*)d_in[7];
  const float* b2 = (const float*)d_in[8];
  const float* Wo = (const float*)d_in[9];
  const float* bo = (const float*)d_in[10];
  float* out = (float*)d_out;

  // Workspace: 16B-aligned big arrays first, then ints.
  unsigned short* x_bf = (unsigned short*)d_ws;      // NN*64 bf16 (6.4 MB)
  unsigned short* agg_bf = x_bf + (size_t)NN * 64;   // NN*64 bf16 (6.4 MB)
  unsigned short* h1_bf = agg_bf + (size_t)NN * 64;  // NN*64 bf16 (6.4 MB)
  unsigned short* col = h1_bf + (size_t)NN * 64;     // KB*BCAP ushort (3.1MB)
  unsigned int* meta = (unsigned int*)(col + (size_t)KB * BCAP);  // NN
  int* bcount = (int*)(meta + NN);                   // KB
  int* gstart = bcount + KB;                         // NG+1
  // ebuf (KB*BCAP uint32 = 6.27MB) aliases agg_bf (6.4MB): consumed by
  // bucket_sort before gather first writes agg_bf.
  unsigned int* ebuf = (unsigned int*)agg_bf;

  hipMemsetAsync(bcount, 0, KB * sizeof(int), stream);

  const int gather_blocks = (NN * 8 + 255) / 256;

  // x -> bf16 (independent of CSR build)
  cvt_f32_bf16<<<(NN * 64 / 8 + 255) / 256, 256, 0, stream>>>(x, x_bf,
                                                              NN * 64 / 8);

  // CSR build (scan-free, 2 kernels) + graph segment bounds
  bucket_scatter<<<SBLK, 256, 0, stream>>>(ei, bcount, ebuf);
  bucket_sort<<<KB, 512, 0, stream>>>(ebuf, bcount, meta, col);
  graph_start_kernel<<<(NG + 64) / 64, 64, 0, stream>>>(batch, gstart);

  // Layer 1
  gather_csr_bf<<<gather_blocks, 256, 0, stream>>>(x_bf, meta, col, agg_bf);
  sage_lin_relu_bf<<<256, 256, 0, stream>>>(agg_bf, x_bf, Wl1, Wr1, b1, h1_bf);

  // Layer 2 (h2 written in-place into agg_bf)
  gather_csr_bf<<<gather_blocks, 256, 0, stream>>>(h1_bf, meta, col, agg_bf);
  sage_lin_relu_bf<<<256, 256, 0, stream>>>(agg_bf, h1_bf, Wl2, Wr2, b2,
                                            agg_bf);

  // Pool (segmented, no atomics) + head
  pool_head_kernel<<<NG, 64, 0, stream>>>(agg_bf, gstart, Wo, bo, out);
}

// Round 8
// 239.682 us; speedup vs baseline: 1.2707x; 1.2707x over previous
//
#include <hip/hip_runtime.h>

// GNN: 2x SAGEConv(sum) + global_add_pool + Linear head.
// N=50000 nodes, E=1e6 edges, D=H=64, G=512 graphs, O=16.
//
// R1: CSR gather replaced scatter atomics (2111 -> 606 us).
// R2: sorted-segment pooling replaced atomic pooling (606 -> 395 us).
// R3: binned counting sort for CSR build (395 -> 367 us).
// R4: bf16 feature storage end-to-end, fp32 accumulate (367 -> 325 us).
// R5: bucket-local degree counting replaced global hist (325 -> 302 us).
// R6: scan-free CSR (good) + 256-block grid-stride GEMM (BAD: 1 block/CU,
//     occupancy 7.8%, GEMM 51 us). Net wash.
// R7: GEMM -> MFMA. relu([agg|h] @ [Wl;Wr] + b) as one K=128,N=64 bf16
// MFMA GEMM (16x16x32): weights pre-transposed to Wt[64][128] bf16 so A/B
// frags are contiguous bf16x8 loads; no LDS; bias in acc init; 782 blocks.

namespace {
constexpr int NN = 50000;
constexpr int NE = 1000000;
constexpr int NG = 512;
constexpr int NO = 16;
constexpr int KB = 98;                      // buckets: dst>>9 (512 nodes)
constexpr int BCAP = 16000;                 // slot capacity per bucket
constexpr int EPT = 8;                      // edges per thread (scatter)
constexpr int EPB = 256 * EPT;              // 2048 edges per block
constexpr int SBLK = (NE + EPB - 1) / EPB;  // 489 blocks
constexpr int SEDGE = 12288;                // staged edges in bucket_sort
}

typedef __attribute__((ext_vector_type(8))) short bf16x8;
typedef __attribute__((ext_vector_type(4))) float f32x4;

__device__ __forceinline__ unsigned short f2bf(float f) {
  unsigned u = __float_as_uint(f);
  u += 0x7FFFu + ((u >> 16) & 1u);  // round-to-nearest-even
  return (unsigned short)(u >> 16);
}
__device__ __forceinline__ float bf2f(unsigned short s) {
  return __uint_as_float(((unsigned)s) << 16);
}

// ---------------- CSR build (scan-free bucketed counting sort) -------------

// Single pass: LDS-binned scatter of packed edges into fixed-capacity
// bucket slots of ebuf. bcount[b] accumulates bucket sizes (48K atomics).
__global__ __launch_bounds__(256) void bucket_scatter(
    const int* __restrict__ ei, int* __restrict__ bcount,
    unsigned int* __restrict__ ebuf) {
  __shared__ int cnt[KB];
  __shared__ int base[KB];
  int t = threadIdx.x;
  if (t < KB) cnt[t] = 0;
  __syncthreads();
  int e0 = blockIdx.x * EPB;
  unsigned int pk[EPT];
#pragma unroll
  for (int i = 0; i < EPT; ++i) {
    int e = e0 + i * 256 + t;
    if (e < NE) {
      unsigned int src = (unsigned int)ei[e];
      unsigned int dst = (unsigned int)ei[NE + e];
      pk[i] = (dst << 16) | src;
      atomicAdd(&cnt[dst >> 9], 1);
    } else {
      pk[i] = 0xFFFFFFFFu;
    }
  }
  __syncthreads();
  if (t < KB) {
    base[t] = t * BCAP + atomicAdd(&bcount[t], cnt[t]);
    cnt[t] = 0;
  }
  __syncthreads();
#pragma unroll
  for (int i = 0; i < EPT; ++i) {
    if (pk[i] != 0xFFFFFFFFu) {
      int b = pk[i] >> 25;  // dst >> 9
      int r = atomicAdd(&cnt[b], 1);
      ebuf[base[b] + r] = pk[i];
    }
  }
}

// One 512-thread block per bucket: stage edges in LDS, LDS degree
// histogram, LDS scan, LDS-cursor placement into col (ushort, bucket
// window), emit meta[node] = (col_beg << 11) | deg.
__global__ __launch_bounds__(512) void bucket_sort(
    const unsigned int* __restrict__ ebuf, const int* __restrict__ bcount,
    unsigned int* __restrict__ meta, unsigned short* __restrict__ col) {
  __shared__ unsigned int se[SEDGE];  // 48 KB edge stage
  __shared__ int cnt[512];
  __shared__ int cur[512];
  int b = blockIdx.x;
  int t = threadIdx.x;
  int n = bcount[b];
  const unsigned int* eb = ebuf + (size_t)b * BCAP;
  cnt[t] = 0;
  __syncthreads();
  for (int j = t; j < n; j += 512) {
    unsigned int p = eb[j];
    if (j < SEDGE) se[j] = p;
    atomicAdd(&cnt[(p >> 16) & 511], 1);
  }
  __syncthreads();
  int deg = cnt[t];
  // Hillis-Steele inclusive scan over 512 (read-all / sync / write / sync)
  for (int off = 1; off < 512; off <<= 1) {
    int u = (t >= off) ? cnt[t - off] : 0;
    __syncthreads();
    cnt[t] += u;
    __syncthreads();
  }
  int excl = cnt[t] - deg;
  cur[t] = excl;
  int node = (b << 9) + t;
  if (node < NN) {
    meta[node] = ((unsigned)(b * BCAP + excl) << 11) | (unsigned)deg;
  }
  __syncthreads();
  unsigned short* cb = col + (size_t)b * BCAP;
  for (int j = t; j < n; j += 512) {
    unsigned int p = (j < SEDGE) ? se[j] : eb[j];
    int d = (p >> 16) & 511;
    int pos = atomicAdd(&cur[d], 1);
    cb[pos] = (unsigned short)(p & 0xFFFFu);
  }
}

// ---------------- bf16 conversion ----------------
__global__ __launch_bounds__(256) void cvt_f32_bf16(
    const float* __restrict__ in, unsigned short* __restrict__ out, int n8) {
  int i = blockIdx.x * 256 + threadIdx.x;
  if (i >= n8) return;
  const float4* p = reinterpret_cast<const float4*>(in + (size_t)i * 8);
  float4 a = p[0], b = p[1];
  uint4 u;
  u.x = (unsigned)f2bf(a.x) | ((unsigned)f2bf(a.y) << 16);
  u.y = (unsigned)f2bf(a.z) | ((unsigned)f2bf(a.w) << 16);
  u.z = (unsigned)f2bf(b.x) | ((unsigned)f2bf(b.y) << 16);
  u.w = (unsigned)f2bf(b.z) | ((unsigned)f2bf(b.w) << 16);
  reinterpret_cast<uint4*>(out)[i] = u;
}

// Wt[n][kk] = (kk<64 ? Wl[kk][n] : Wr[kk-64][n]) as bf16, for both layers.
// 16384 threads: id -> {layer, n (0..63), kk (0..127)}.
__global__ __launch_bounds__(256) void prep_weights(
    const float* __restrict__ Wl1, const float* __restrict__ Wr1,
    const float* __restrict__ Wl2, const float* __restrict__ Wr2,
    unsigned short* __restrict__ Wt1, unsigned short* __restrict__ Wt2) {
  int id = blockIdx.x * 256 + threadIdx.x;
  if (id >= 16384) return;
  int half = id >> 13;
  int e = id & 8191;
  int nrow = e >> 7;
  int kk = e & 127;
  const float* Wl = half ? Wl2 : Wl1;
  const float* Wr = half ? Wr2 : Wr1;
  unsigned short* Wt = half ? Wt2 : Wt1;
  float v = (kk < 64) ? Wl[kk * 64 + nrow] : Wr[(kk - 64) * 64 + nrow];
  Wt[nrow * 128 + kk] = f2bf(v);
}

// ---------------- aggregation (gather, bf16, no atomics) ----------------
// 8 threads per node, one 16B uint4 (8 bf16) per thread per neighbor:
// each edge touches exactly one 128B line. fp32 accumulate, bf16 store.
__global__ __launch_bounds__(256) void gather_csr_bf(
    const unsigned short* __restrict__ feat, const unsigned int* __restrict__ meta,
    const unsigned short* __restrict__ col, unsigned short* __restrict__ agg) {
  int gid = blockIdx.x * 256 + threadIdx.x;
  int v = gid >> 3;
  int q = gid & 7;
  if (v >= NN) return;
  unsigned int m = meta[v];
  int beg = (int)(m >> 11);
  int end = beg + (int)(m & 2047u);
  float acc[8] = {0.f, 0.f, 0.f, 0.f, 0.f, 0.f, 0.f, 0.f};
  const uint4* fb = reinterpret_cast<const uint4*>(feat);
  for (int j = beg; j < end; ++j) {
    int s = col[j];
    uint4 u = fb[(size_t)s * 8 + q];
    acc[0] += __uint_as_float(u.x << 16);
    acc[1] += __uint_as_float(u.x & 0xFFFF0000u);
    acc[2] += __uint_as_float(u.y << 16);
    acc[3] += __uint_as_float(u.y & 0xFFFF0000u);
    acc[4] += __uint_as_float(u.z << 16);
    acc[5] += __uint_as_float(u.z & 0xFFFF0000u);
    acc[6] += __uint_as_float(u.w << 16);
    acc[7] += __uint_as_float(u.w & 0xFFFF0000u);
  }
  uint4 o;
  o.x = (unsigned)f2bf(acc[0]) | ((unsigned)f2bf(acc[1]) << 16);
  o.y = (unsigned)f2bf(acc[2]) | ((unsigned)f2bf(acc[3]) << 16);
  o.z = (unsigned)f2bf(acc[4]) | ((unsigned)f2bf(acc[5]) << 16);
  o.w = (unsigned)f2bf(acc[6]) | ((unsigned)f2bf(acc[7]) << 16);
  reinterpret_cast<uint4*>(agg)[(size_t)v * 8 + q] = o;
}

// ---------------- MFMA GEMM (bf16 in/out, fp32 acc) ----------------
// out[row,:] = relu([A_row | H_row] @ Wt^T + b), K=128, N=64.
// One wave = 16 rows x 64 cols = 16x v_mfma_f32_16x16x32_bf16.
// Fragment maps (verified, learn_hip m89/m120):
//   A: lane m=lane&15, k=quad*8+j (contig bf16x8 from the row)
//   B: lane n=lane&15, k=quad*8+j (contig bf16x8 from transposed Wt[n][k])
//   C: col=lane&15, row=quad*4+reg
// No LDS: Wt is 16 KB, L1-resident. Layer 2 runs in-place (out==A): rows
// are partitioned per wave; A loads are register-consumed by the MFMAs
// before any store issues. A/Hr/out deliberately NOT __restrict__.
__global__ __launch_bounds__(256) void sage_mfma(
    const unsigned short* A, const unsigned short* Hr,
    const unsigned short* __restrict__ Wt, const float* __restrict__ bias,
    unsigned short* out) {
  int tid = threadIdx.x;
  int wave = tid >> 6;
  int lane = tid & 63;
  int n = lane & 15;  // A-row-within-tile AND B/C column-within-tile
  int q = lane >> 4;  // quad
  long base = ((long)blockIdx.x * 4 + wave) * 16;
  if (base >= NN) return;
  long rowA = base + n;
  if (rowA >= NN) rowA = NN - 1;  // clamped dup read; store predicated below

  f32x4 acc[4];
#pragma unroll
  for (int t = 0; t < 4; ++t) {
    float bv = bias[t * 16 + n];
    acc[t][0] = bv;
    acc[t][1] = bv;
    acc[t][2] = bv;
    acc[t][3] = bv;
  }

  const unsigned short* arow = A + rowA * 64;
  const unsigned short* hrow = Hr + rowA * 64;
  bf16x8 af[4];
  af[0] = *(const bf16x8*)(arow + q * 8);        // k 0..31
  af[1] = *(const bf16x8*)(arow + 32 + q * 8);   // k 32..63
  af[2] = *(const bf16x8*)(hrow + q * 8);        // k 64..95
  af[3] = *(const bf16x8*)(hrow + 32 + q * 8);   // k 96..127

#pragma unroll
  for (int t = 0; t < 4; ++t) {
    const unsigned short* wrow = Wt + (size_t)(t * 16 + n) * 128 + q * 8;
#pragma unroll
    for (int s = 0; s < 4; ++s) {
      bf16x8 bfm = *(const bf16x8*)(wrow + s * 32);
      acc[t] =
          __builtin_amdgcn_mfma_f32_16x16x32_bf16(af[s], bfm, acc[t], 0, 0, 0);
    }
  }

#pragma unroll
  for (int r = 0; r < 4; ++r) {
    long rowc = base + q * 4 + r;
    if (rowc < NN) {
      unsigned short* orow = out + rowc * 64;
#pragma unroll
      for (int t = 0; t < 4; ++t) {
        orow[t * 16 + n] = f2bf(fmaxf(acc[t][r], 0.f));
      }
    }
  }
}

// ---------------- pooling (sorted-segment reduction) + head ----------------

__global__ __launch_bounds__(64) void graph_start_kernel(
    const int* __restrict__ batch, int* __restrict__ gstart) {
  int g = blockIdx.x * 64 + threadIdx.x;
  if (g > NG) return;
  int lo = 0, hi = NN;
  while (lo < hi) {
    int mid = (lo + hi) >> 1;
    if (batch[mid] < g)
      lo = mid + 1;
    else
      hi = mid;
  }
  gstart[g] = lo;
}

__global__ __launch_bounds__(64) void pool_head_kernel(
    const unsigned short* __restrict__ h2, const int* __restrict__ gstart,
    const float* __restrict__ Wo, const float* __restrict__ bo,
    float* __restrict__ out) {
  __shared__ float sm[64];
  int g = blockIdx.x;
  int c = threadIdx.x;
  int beg = gstart[g], end = gstart[g + 1];
  float acc = 0.f;
  for (int i = beg; i < end; ++i) acc += bf2f(h2[(size_t)i * 64 + c]);
  sm[c] = acc;
  __syncthreads();
  if (c < NO) {
    float o = bo[c];
#pragma unroll
    for (int k = 0; k < 64; ++k) o += sm[k] * Wo[k * 16 + c];
    out[g * 16 + c] = o;
  }
}

extern "C" void kernel_launch(void* const* d_in, const int* in_sizes, int n_in,
                              void* d_out, int out_size, void* d_ws,
                              size_t ws_size, hipStream_t stream) {
  const float* x = (const float*)d_in[0];
  const int* ei = (const int*)d_in[1];
  const int* batch = (const int*)d_in[2];
  const float* Wl1 = (const float*)d_in[3];
  const float* Wr1 = (const float*)d_in[4];
  const float* b1 = (const float*)d_in[5];
  const float* Wl2 = (const float*)d_in[6];
  const float* Wr2 = (const float*)d_in[7];
  const float* b2 = (const float*)d_in[8];
  const float* Wo = (const float*)d_in[9];
  const float* bo = (const float*)d_in[10];
  float* out = (float*)d_out;

  // Workspace: 16B-aligned big arrays first, then ints.
  unsigned short* x_bf = (unsigned short*)d_ws;      // NN*64 bf16 (6.4 MB)
  unsigned short* agg_bf = x_bf + (size_t)NN * 64;   // NN*64 bf16 (6.4 MB)
  unsigned short* h1_bf = agg_bf + (size_t)NN * 64;  // NN*64 bf16 (6.4 MB)
  unsigned short* col = h1_bf + (size_t)NN * 64;     // KB*BCAP ushort (3.1MB)
  unsigned short* Wt1 = col + (size_t)KB * BCAP;     // 64*128 bf16
  unsigned short* Wt2 = Wt1 + 64 * 128;              // 64*128 bf16
  unsigned int* meta = (unsigned int*)(Wt2 + 64 * 128);  // NN
  int* bcount = (int*)(meta + NN);                   // KB
  int* gstart = bcount + KB;                         // NG+1
  // ebuf (KB*BCAP uint32 = 6.27MB) aliases agg_bf (6.4MB): consumed by
  // bucket_sort before gather first writes agg_bf.
  unsigned int* ebuf = (unsigned int*)agg_bf;

  hipMemsetAsync(bcount, 0, KB * sizeof(int), stream);

  const int gather_blocks = (NN * 8 + 255) / 256;
  const int gemm_blocks = (NN + 63) / 64;  // 782: 4 waves x 16 rows

  // x -> bf16, weights -> transposed bf16 (independent of CSR build)
  cvt_f32_bf16<<<(NN * 64 / 8 + 255) / 256, 256, 0, stream>>>(x, x_bf,
                                                              NN * 64 / 8);
  prep_weights<<<64, 256, 0, stream>>>(Wl1, Wr1, Wl2, Wr2, Wt1, Wt2);

  // CSR build (scan-free, 2 kernels) + graph segment bounds
  bucket_scatter<<<SBLK, 256, 0, stream>>>(ei, bcount, ebuf);
  bucket_sort<<<KB, 512, 0, stream>>>(ebuf, bcount, meta, col);
  graph_start_kernel<<<(NG + 64) / 64, 64, 0, stream>>>(batch, gstart);

  // Layer 1
  gather_csr_bf<<<gather_blocks, 256, 0, stream>>>(x_bf, meta, col, agg_bf);
  sage_mfma<<<gemm_blocks, 256, 0, stream>>>(agg_bf, x_bf, Wt1, b1, h1_bf);

  // Layer 2 (h2 written in-place into agg_bf)
  gather_csr_bf<<<gather_blocks, 256, 0, stream>>>(h1_bf, meta, col, agg_bf);
  sage_mfma<<<gemm_blocks, 256, 0, stream>>>(agg_bf, h1_bf, Wt2, b2, agg_bf);

  // Pool (segmented, no atomics) + head
  pool_head_kernel<<<NG, 64, 0, stream>>>(agg_bf, gstart, Wo, bo, out);
}